// Round 12
// baseline (458.729 us; speedup 1.0000x reference)
//
#include <hip/hip_runtime.h>

// ChebNet round 12: revert CSR to R10 (measured-good), fuse prop2 into the
// cheb MFMA kernel (X2 lives only in LDS), fuse feature->bf16 scaling into
// k_local. Standalone prop = R10 4-group version. 11 kernels total.

typedef unsigned short ushort_t;
typedef __attribute__((ext_vector_type(8))) short v8s;
typedef __attribute__((ext_vector_type(4))) float v4f;

__device__ inline ushort_t f2bf(float f) {  // RNE float->bf16
    unsigned u = __float_as_uint(f);
    return (ushort_t)((u + 0x7FFFu + ((u >> 16) & 1u)) >> 16);
}
__device__ inline float bf2f(ushort_t h) {
    return __uint_as_float(((unsigned)h) << 16);
}

#define BSH 9
#define BSZ (1 << BSH)
#define CHUNK 4096

// ---------- CSR build (R10 version) ----------

__global__ __launch_bounds__(256) void k_bhist(const int* __restrict__ dst,
                                               int* __restrict__ gbase, int E, int NB) {
    __shared__ int h[1024];
    for (int i = threadIdx.x; i < NB; i += 256) h[i] = 0;
    __syncthreads();
    for (int i = blockIdx.x * blockDim.x + threadIdx.x; i < E; i += gridDim.x * blockDim.x)
        atomicAdd(&h[dst[i] >> BSH], 1);
    __syncthreads();
    for (int i = threadIdx.x; i < NB; i += 256)
        if (h[i]) atomicAdd(&gbase[i], h[i]);
}

__global__ void k_bscan(int* __restrict__ gbase, int* __restrict__ gcur, int NB) {
    __shared__ int sh[1024];
    int t = threadIdx.x;
    int v = (t < NB) ? gbase[t] : 0;
    sh[t] = v;
    __syncthreads();
    for (int off = 1; off < 1024; off <<= 1) {
        int u = 0;
        if (t >= off) u = sh[t - off];
        __syncthreads();
        sh[t] += u;
        __syncthreads();
    }
    if (t < NB) {
        int excl = sh[t] - v;
        gbase[t] = excl;
        gcur[t] = excl;
    }
}

__global__ __launch_bounds__(256) void k_bucket2(
    const int* __restrict__ src, const int* __restrict__ dst,
    int* __restrict__ gcur, int2* __restrict__ eb, int E, int NB) {
    __shared__ int ls[CHUNK];
    __shared__ int ld[CHUNK];
    __shared__ int hist[1024];
    __shared__ int bbase[1024];
    int t = threadIdx.x;
    int base = blockIdx.x * CHUNK;
    int count = E - base;
    if (count > CHUNK) count = CHUNK;
    for (int i = t; i < NB; i += 256) hist[i] = 0;
    __syncthreads();
    for (int i = t; i < count; i += 256) {
        int s = src[base + i];
        int d = dst[base + i];
        ls[i] = s;
        ld[i] = d;
        atomicAdd(&hist[d >> BSH], 1);
    }
    __syncthreads();
    for (int b = t; b < NB; b += 256) {
        int c = hist[b];
        bbase[b] = c ? atomicAdd(&gcur[b], c) : 0;
        hist[b] = 0;
    }
    __syncthreads();
    for (int i = t; i < count; i += 256) {
        int d = ld[i];
        int b = d >> BSH;
        int off = atomicAdd(&hist[b], 1);
        eb[bbase[b] + off] = make_int2(ls[i], d);
    }
}

// per-bucket finalize + fused scaled-bf16 feature shadow (Fb = bf16(x*dinv))
__global__ __launch_bounds__(256) void k_local(
    const int2* __restrict__ eb, const int* __restrict__ gbase,
    int* __restrict__ col, int* __restrict__ row_ptr,
    float* __restrict__ dinv, const float* __restrict__ features,
    ushort_t* __restrict__ Fb, int N, int E, int NB) {
    __shared__ int cnt[BSZ];
    __shared__ int tsum[256];
    int t = threadIdx.x;
    int b = blockIdx.x;
    int d0 = b << BSH;
    cnt[2 * t] = 0;
    cnt[2 * t + 1] = 0;
    __syncthreads();
    int beg = gbase[b];
    int end = (b + 1 < NB) ? gbase[b + 1] : E;
    for (int i = beg + t; i < end; i += 256)
        atomicAdd(&cnt[eb[i].y - d0], 1);
    __syncthreads();
    int c0 = cnt[2 * t], c1 = cnt[2 * t + 1];
    int mysum = c0 + c1;
    tsum[t] = mysum;
    __syncthreads();
    for (int off = 1; off < 256; off <<= 1) {
        int u = 0;
        if (t >= off) u = tsum[t - off];
        __syncthreads();
        tsum[t] += u;
        __syncthreads();
    }
    int rbase = beg + tsum[t] - mysum;
    float di0 = rsqrtf(fmaxf((float)c0, 1.0f));
    float di1 = rsqrtf(fmaxf((float)c1, 1.0f));
    int d = d0 + 2 * t;
    if (d < N) {
        row_ptr[d] = rbase;
        dinv[d] = di0;
    }
    if (d + 1 < N) {
        row_ptr[d + 1] = rbase + c0;
        dinv[d + 1] = di1;
    }
    cnt[2 * t] = rbase;
    cnt[2 * t + 1] = rbase + c0;
    __syncthreads();
    for (int i = beg + t; i < end; i += 256) {
        int2 e = eb[i];
        int p = atomicAdd(&cnt[e.y - d0], 1);
        col[p] = e.x;
    }
    if (b == NB - 1 && t == 0) row_ptr[N] = E;
    // ---- fused: write scaled bf16 feature rows for this bucket ----
    __syncthreads();
    ((float*)cnt)[2 * t] = di0;
    ((float*)cnt)[2 * t + 1] = di1;
    __syncthreads();
    int nmax = N - d0;
    if (nmax > BSZ) nmax = BSZ;
    for (int i = t; i < nmax * 16; i += 256) {
        int nl = i >> 4, f4 = (i & 15) * 4;
        float s = ((float*)cnt)[nl];
        float4 v = *(const float4*)&features[(size_t)(d0 + nl) * 64 + f4];
        ushort4 o;
        o.x = f2bf(v.x * s); o.y = f2bf(v.y * s); o.z = f2bf(v.z * s); o.w = f2bf(v.w * s);
        *(ushort4*)&Fb[(size_t)(d0 + nl) * 64 + f4] = o;
    }
}

// ---------- weight prep: fp32 -> bf16 transposed ----------
__global__ void k_wprep(const float* __restrict__ W1, const float* __restrict__ W2,
                        const float* __restrict__ Wm1, const float* __restrict__ Wm2,
                        ushort_t* __restrict__ W1t, ushort_t* __restrict__ W2t,
                        ushort_t* __restrict__ Wm1t, ushort_t* __restrict__ Wm2t) {
    int i = blockIdx.x * 256 + threadIdx.x;
    if (i < 12288) { int k = i >> 6, n = i & 63; W1t[n * 192 + k] = f2bf(W1[i]); return; }
    i -= 12288;
    if (i < 12288) { int k = i >> 6, n = i & 63; W2t[n * 192 + k] = f2bf(W2[i]); return; }
    i -= 12288;
    if (i < 4096) { int k = i >> 6, n = i & 63; Wm1t[n * 64 + k] = f2bf(Wm1[i]); return; }
    i -= 4096;
    if (i < 2048) { int k = i >> 5, n = i & 31; Wm2t[n * 64 + k] = f2bf(Wm2[i]); }
}

// ---------- standalone prop (R10 4-group): X1 = -di^2 * sum (scaled out) ----------
__global__ __launch_bounds__(256) void k_prop1(
    const ushort_t* __restrict__ Xb, const int* __restrict__ rp,
    const int* __restrict__ col, const float* __restrict__ dinv,
    ushort_t* __restrict__ OUTB, int N) {
    int wid = (blockIdx.x * blockDim.x + threadIdx.x) >> 6;
    int lane = threadIdx.x & 63;
    if (wid >= N) return;
    int g = lane >> 4;
    int fl = (lane & 15) * 4;
    int beg = rp[wid], end = rp[wid + 1];
    float4 a0 = make_float4(0.f, 0.f, 0.f, 0.f);
    float4 a1 = make_float4(0.f, 0.f, 0.f, 0.f);
    int e = beg + g;
    for (; e + 4 < end; e += 8) {
        int s0 = col[e], s1 = col[e + 4];
        ushort4 u0 = *(const ushort4*)&Xb[(size_t)s0 * 64 + fl];
        ushort4 u1 = *(const ushort4*)&Xb[(size_t)s1 * 64 + fl];
        a0.x += bf2f(u0.x); a0.y += bf2f(u0.y); a0.z += bf2f(u0.z); a0.w += bf2f(u0.w);
        a1.x += bf2f(u1.x); a1.y += bf2f(u1.y); a1.z += bf2f(u1.z); a1.w += bf2f(u1.w);
    }
    if (e < end) {
        int s0 = col[e];
        ushort4 u0 = *(const ushort4*)&Xb[(size_t)s0 * 64 + fl];
        a0.x += bf2f(u0.x); a0.y += bf2f(u0.y); a0.z += bf2f(u0.z); a0.w += bf2f(u0.w);
    }
    float4 acc;
    acc.x = a0.x + a1.x;
    acc.y = a0.y + a1.y;
    acc.z = a0.z + a1.z;
    acc.w = a0.w + a1.w;
    acc.x += __shfl_xor(acc.x, 16);
    acc.y += __shfl_xor(acc.y, 16);
    acc.z += __shfl_xor(acc.z, 16);
    acc.w += __shfl_xor(acc.w, 16);
    acc.x += __shfl_xor(acc.x, 32);
    acc.y += __shfl_xor(acc.y, 32);
    acc.z += __shfl_xor(acc.z, 32);
    acc.w += __shfl_xor(acc.w, 32);
    if (g == 0) {
        float di = dinv[wid];
        float m = -di * di;
        ushort4 ob;
        ob.x = f2bf(m * acc.x);
        ob.y = f2bf(m * acc.y);
        ob.z = f2bf(m * acc.z);
        ob.w = f2bf(m * acc.w);
        *(ushort4*)&OUTB[(size_t)wid * 64 + fl] = ob;
    }
}

// ---------- fused prop2 + cheb MFMA ----------
// Phase A: per wave, compute X2 rows (gather X1, MODE2 epilogue) for its 16
// nodes -> LDS. Phase B: MFMA over [X0|X1|X2] with X2 from LDS.
// X0, X1 are dinv-scaled (acc_s); X2 unscaled (acc_u);
// epilogue y = acc_s/dinv + acc_u + b; SCALE_OUT writes bf16(y*dinv).
template <bool SCALE_OUT>
__global__ __launch_bounds__(256) void k_cheb_fused(
    const ushort_t* __restrict__ X0, const ushort_t* __restrict__ X1,
    const int* __restrict__ rp, const int* __restrict__ col,
    const float* __restrict__ dinv,
    const ushort_t* __restrict__ Wt, const float* __restrict__ b,
    ushort_t* __restrict__ Yb, int N) {
    __shared__ ushort_t X2s[64][72];  // 144B rows: 16B-aligned, 2-way banks max
    int wave = threadIdx.x >> 6, lane = threadIdx.x & 63;
    int node0 = blockIdx.x * 64;

    // ---- phase A ----
    {
        int g = lane >> 4;
        int fl = (lane & 15) * 4;
        for (int i = 0; i < 16; i++) {
            int node = node0 + wave * 16 + i;
            if (node >= N) break;
            int beg = rp[node], end = rp[node + 1];
            float4 a0 = make_float4(0.f, 0.f, 0.f, 0.f);
            float4 a1 = make_float4(0.f, 0.f, 0.f, 0.f);
            int e = beg + g;
            for (; e + 4 < end; e += 8) {
                int s0 = col[e], s1 = col[e + 4];
                ushort4 u0 = *(const ushort4*)&X1[(size_t)s0 * 64 + fl];
                ushort4 u1 = *(const ushort4*)&X1[(size_t)s1 * 64 + fl];
                a0.x += bf2f(u0.x); a0.y += bf2f(u0.y); a0.z += bf2f(u0.z); a0.w += bf2f(u0.w);
                a1.x += bf2f(u1.x); a1.y += bf2f(u1.y); a1.z += bf2f(u1.z); a1.w += bf2f(u1.w);
            }
            if (e < end) {
                int s0 = col[e];
                ushort4 u0 = *(const ushort4*)&X1[(size_t)s0 * 64 + fl];
                a0.x += bf2f(u0.x); a0.y += bf2f(u0.y); a0.z += bf2f(u0.z); a0.w += bf2f(u0.w);
            }
            float4 acc;
            acc.x = a0.x + a1.x;
            acc.y = a0.y + a1.y;
            acc.z = a0.z + a1.z;
            acc.w = a0.w + a1.w;
            acc.x += __shfl_xor(acc.x, 16);
            acc.y += __shfl_xor(acc.y, 16);
            acc.z += __shfl_xor(acc.z, 16);
            acc.w += __shfl_xor(acc.w, 16);
            acc.x += __shfl_xor(acc.x, 32);
            acc.y += __shfl_xor(acc.y, 32);
            acc.z += __shfl_xor(acc.z, 32);
            acc.w += __shfl_xor(acc.w, 32);
            if (g == 0) {
                float di = dinv[node];
                ushort4 x0u = *(const ushort4*)&X0[(size_t)node * 64 + fl];
                float m = -2.0f * di;
                float rd = 1.0f / di;
                ushort4 ob;
                ob.x = f2bf(fmaf(m, acc.x, -rd * bf2f(x0u.x)));
                ob.y = f2bf(fmaf(m, acc.y, -rd * bf2f(x0u.y)));
                ob.z = f2bf(fmaf(m, acc.z, -rd * bf2f(x0u.z)));
                ob.w = f2bf(fmaf(m, acc.w, -rd * bf2f(x0u.w)));
                *(ushort4*)&X2s[wave * 16 + i][fl] = ob;
            }
        }
    }
    __syncthreads();

    // ---- phase B ----
    int n16 = lane & 15, q = lane >> 4;
    int arow = node0 + wave * 16 + n16;
    const ushort_t* Xc[2] = {X0, X1};
    v4f acc_s[4], acc_u[4];
#pragma unroll
    for (int t = 0; t < 4; t++) {
        acc_s[t] = (v4f){0.f, 0.f, 0.f, 0.f};
        acc_u[t] = (v4f){0.f, 0.f, 0.f, 0.f};
    }
#pragma unroll
    for (int ks = 0; ks < 6; ks++) {
        int c = ks >> 1;
        int kk = (ks & 1) * 32 + q * 8;
        v8s av = {0, 0, 0, 0, 0, 0, 0, 0};
        if (c < 2) {
            if (arow < N) av = *(const v8s*)&Xc[c][(size_t)arow * 64 + kk];
        } else {
            av = *(const v8s*)&X2s[wave * 16 + n16][kk];
        }
#pragma unroll
        for (int t = 0; t < 4; t++) {
            v8s bv = *(const v8s*)&Wt[(size_t)(t * 16 + n16) * 192 + ks * 32 + q * 8];
            if (c < 2)
                acc_s[t] = __builtin_amdgcn_mfma_f32_16x16x32_bf16(av, bv, acc_s[t], 0, 0, 0);
            else
                acc_u[t] = __builtin_amdgcn_mfma_f32_16x16x32_bf16(av, bv, acc_u[t], 0, 0, 0);
        }
    }
    int rbase = node0 + wave * 16 + q * 4;
#pragma unroll
    for (int r = 0; r < 4; r++) {
        int row = rbase + r;
        if (row < N) {
            float dv = dinv[row];
            float rd = 1.0f / dv;
            float s = SCALE_OUT ? dv : 1.0f;
#pragma unroll
            for (int t = 0; t < 4; t++) {
                float y = fmaf(rd, acc_s[t][r], acc_u[t][r]) + b[t * 16 + n16];
                y = fmaxf(y, 0.0f);
                Yb[(size_t)row * 64 + t * 16 + n16] = f2bf(s * y);
            }
        }
    }
}

// ---------- MLP head via MFMA (R10) ----------
__global__ __launch_bounds__(256) void k_mlp_mfma(
    const ushort_t* __restrict__ Hb, const ushort_t* __restrict__ W1t,
    const float* __restrict__ b1, const ushort_t* __restrict__ W2t,
    const float* __restrict__ b2, float* __restrict__ out, int N) {
    __shared__ ushort_t Hs[64][76];
    int wave = threadIdx.x >> 6, lane = threadIdx.x & 63;
    int n16 = lane & 15, q = lane >> 4;
    int node0 = blockIdx.x * 64;
    int arow = node0 + wave * 16 + n16;

    v4f acc[4];
#pragma unroll
    for (int t = 0; t < 4; t++) acc[t] = (v4f){0.f, 0.f, 0.f, 0.f};
#pragma unroll
    for (int ks = 0; ks < 2; ks++) {
        v8s av = {0, 0, 0, 0, 0, 0, 0, 0};
        if (arow < N) av = *(const v8s*)&Hb[(size_t)arow * 64 + ks * 32 + q * 8];
#pragma unroll
        for (int t = 0; t < 4; t++) {
            v8s bv = *(const v8s*)&W1t[(size_t)(t * 16 + n16) * 64 + ks * 32 + q * 8];
            acc[t] = __builtin_amdgcn_mfma_f32_16x16x32_bf16(av, bv, acc[t], 0, 0, 0);
        }
    }
    int lr = wave * 16 + q * 4;
#pragma unroll
    for (int r = 0; r < 4; r++)
#pragma unroll
        for (int t = 0; t < 4; t++) {
            float y = acc[t][r] + b1[t * 16 + n16];
            Hs[lr + r][t * 16 + n16] = f2bf(fmaxf(y, 0.0f));
        }
    __syncthreads();

    v4f a2[2];
    a2[0] = (v4f){0.f, 0.f, 0.f, 0.f};
    a2[1] = (v4f){0.f, 0.f, 0.f, 0.f};
#pragma unroll
    for (int ks = 0; ks < 2; ks++) {
        v8s av = *(const v8s*)&Hs[wave * 16 + n16][ks * 32 + q * 8];
#pragma unroll
        for (int t = 0; t < 2; t++) {
            v8s bv = *(const v8s*)&W2t[(size_t)(t * 16 + n16) * 64 + ks * 32 + q * 8];
            a2[t] = __builtin_amdgcn_mfma_f32_16x16x32_bf16(av, bv, a2[t], 0, 0, 0);
        }
    }
    int rbase = node0 + wave * 16 + q * 4;
#pragma unroll
    for (int r = 0; r < 4; r++) {
        int row = rbase + r;
        if (row < N) {
#pragma unroll
            for (int t = 0; t < 2; t++)
                out[(size_t)row * 32 + t * 16 + n16] = a2[t][r] + b2[t * 16 + n16];
        }
    }
}

extern "C" void kernel_launch(void* const* d_in, const int* in_sizes, int n_in,
                              void* d_out, int out_size, void* d_ws, size_t ws_size,
                              hipStream_t stream) {
    const float* features = (const float*)d_in[0];
    const int* src = (const int*)d_in[1];
    const int* dst = (const int*)d_in[2];
    const float* W1 = (const float*)d_in[4];
    const float* b1 = (const float*)d_in[5];
    const float* W2 = (const float*)d_in[6];
    const float* b2 = (const float*)d_in[7];
    const float* Wm1 = (const float*)d_in[8];
    const float* bm1 = (const float*)d_in[9];
    const float* Wm2 = (const float*)d_in[10];
    const float* bm2 = (const float*)d_in[11];
    float* out = (float*)d_out;

    int N = in_sizes[0] / 64;
    int E = in_sizes[1];
    int NB = (N + BSZ - 1) >> BSH;

    float* ws = (float*)d_ws;
    float* dinv = ws;                           // [N]
    int* row_ptr = (int*)(dinv + N);            // [N+1]
    int* gbase = row_ptr + (N + 1);             // [1024]
    int* gcur = gbase + 1024;                   // [1024]
    int* col = gcur + 1024;                     // [E]
    int2* eb = (int2*)(((uintptr_t)(col + E) + 7) & ~(uintptr_t)7);  // [E]
    ushort_t* Fb  = (ushort_t*)(eb + E);        // [N*64] scaled
    ushort_t* X1b = Fb  + (size_t)N * 64;       // scaled
    ushort_t* H1b = X1b + (size_t)N * 64;       // scaled
    ushort_t* H2b = H1b + (size_t)N * 64;       // unscaled
    ushort_t* W1t = H2b + (size_t)N * 64;       // [64*192]
    ushort_t* W2t = W1t + 64 * 192;
    ushort_t* Wm1t = W2t + 64 * 192;            // [64*64]
    ushort_t* Wm2t = Wm1t + 64 * 64;            // [32*64]

    int pblk = (N * 64 + 255) / 256;
    int gblk = (N + 63) / 64;
    int bblk = (E + CHUNK - 1) / CHUNK;

    // weight prep
    k_wprep<<<(30720 + 255) / 256, 256, 0, stream>>>(W1, W2, Wm1, Wm2, W1t, W2t, Wm1t, Wm2t);

    // CSR build (R10)
    hipMemsetAsync(gbase, 0, NB * sizeof(int), stream);
    k_bhist<<<512, 256, 0, stream>>>(dst, gbase, E, NB);
    k_bscan<<<1, 1024, 0, stream>>>(gbase, gcur, NB);
    k_bucket2<<<bblk, 256, 0, stream>>>(src, dst, gcur, eb, E, NB);
    k_local<<<NB, 256, 0, stream>>>(eb, gbase, col, row_ptr, dinv, features, Fb, N, E, NB);

    // layer 1
    k_prop1<<<pblk, 256, 0, stream>>>(Fb, row_ptr, col, dinv, X1b, N);
    k_cheb_fused<true><<<gblk, 256, 0, stream>>>(Fb, X1b, row_ptr, col, dinv, W1t, b1, H1b, N);

    // layer 2
    k_prop1<<<pblk, 256, 0, stream>>>(H1b, row_ptr, col, dinv, X1b, N);
    k_cheb_fused<false><<<gblk, 256, 0, stream>>>(H1b, X1b, row_ptr, col, dinv, W2t, b2, H2b, N);

    // MLP head
    k_mlp_mfma<<<gblk, 256, 0, stream>>>(H2b, Wm1t, bm1, Wm2t, bm2, out, N);
}

// Round 14
// 407.038 us; speedup vs baseline: 1.1270x; 1.1270x over previous
//
#include <hip/hip_runtime.h>

// ChebNet round 14: best-known config = R10 (396us measured) + fused
// feature->scaled-bf16 shadow inside k_local (drops k_tobf16 dispatch).
// Cooperative mega-kernel (R13) failed on this harness -> abandoned.
// Props are fabric-byte bound at ~2.8 TB/s (R11 evidence); GEMMs are MFMA.

typedef unsigned short ushort_t;
typedef __attribute__((ext_vector_type(8))) short v8s;
typedef __attribute__((ext_vector_type(4))) float v4f;

__device__ inline ushort_t f2bf(float f) {  // RNE float->bf16
    unsigned u = __float_as_uint(f);
    return (ushort_t)((u + 0x7FFFu + ((u >> 16) & 1u)) >> 16);
}
__device__ inline float bf2f(ushort_t h) {
    return __uint_as_float(((unsigned)h) << 16);
}

#define BSH 9
#define BSZ (1 << BSH)
#define CHUNK 4096

// ---------- CSR build (R10, measured-good) ----------

__global__ __launch_bounds__(256) void k_bhist(const int* __restrict__ dst,
                                               int* __restrict__ gbase, int E, int NB) {
    __shared__ int h[1024];
    for (int i = threadIdx.x; i < NB; i += 256) h[i] = 0;
    __syncthreads();
    for (int i = blockIdx.x * blockDim.x + threadIdx.x; i < E; i += gridDim.x * blockDim.x)
        atomicAdd(&h[dst[i] >> BSH], 1);
    __syncthreads();
    for (int i = threadIdx.x; i < NB; i += 256)
        if (h[i]) atomicAdd(&gbase[i], h[i]);
}

__global__ void k_bscan(int* __restrict__ gbase, int* __restrict__ gcur, int NB) {
    __shared__ int sh[1024];
    int t = threadIdx.x;
    int v = (t < NB) ? gbase[t] : 0;
    sh[t] = v;
    __syncthreads();
    for (int off = 1; off < 1024; off <<= 1) {
        int u = 0;
        if (t >= off) u = sh[t - off];
        __syncthreads();
        sh[t] += u;
        __syncthreads();
    }
    if (t < NB) {
        int excl = sh[t] - v;
        gbase[t] = excl;
        gcur[t] = excl;
    }
}

__global__ __launch_bounds__(256) void k_bucket2(
    const int* __restrict__ src, const int* __restrict__ dst,
    int* __restrict__ gcur, int2* __restrict__ eb, int E, int NB) {
    __shared__ int ls[CHUNK];
    __shared__ int ld[CHUNK];
    __shared__ int hist[1024];
    __shared__ int bbase[1024];
    int t = threadIdx.x;
    int base = blockIdx.x * CHUNK;
    int count = E - base;
    if (count > CHUNK) count = CHUNK;
    for (int i = t; i < NB; i += 256) hist[i] = 0;
    __syncthreads();
    for (int i = t; i < count; i += 256) {
        int s = src[base + i];
        int d = dst[base + i];
        ls[i] = s;
        ld[i] = d;
        atomicAdd(&hist[d >> BSH], 1);
    }
    __syncthreads();
    for (int b = t; b < NB; b += 256) {
        int c = hist[b];
        bbase[b] = c ? atomicAdd(&gcur[b], c) : 0;
        hist[b] = 0;
    }
    __syncthreads();
    for (int i = t; i < count; i += 256) {
        int d = ld[i];
        int b = d >> BSH;
        int off = atomicAdd(&hist[b], 1);
        eb[bbase[b] + off] = make_int2(ls[i], d);
    }
}

// per-bucket finalize + fused scaled-bf16 feature shadow (Fb = bf16(x*dinv))
__global__ __launch_bounds__(256) void k_local(
    const int2* __restrict__ eb, const int* __restrict__ gbase,
    int* __restrict__ col, int* __restrict__ row_ptr,
    float* __restrict__ dinv, const float* __restrict__ features,
    ushort_t* __restrict__ Fb, int N, int E, int NB) {
    __shared__ int cnt[BSZ];
    __shared__ int tsum[256];
    int t = threadIdx.x;
    int b = blockIdx.x;
    int d0 = b << BSH;
    cnt[2 * t] = 0;
    cnt[2 * t + 1] = 0;
    __syncthreads();
    int beg = gbase[b];
    int end = (b + 1 < NB) ? gbase[b + 1] : E;
    for (int i = beg + t; i < end; i += 256)
        atomicAdd(&cnt[eb[i].y - d0], 1);
    __syncthreads();
    int c0 = cnt[2 * t], c1 = cnt[2 * t + 1];
    int mysum = c0 + c1;
    tsum[t] = mysum;
    __syncthreads();
    for (int off = 1; off < 256; off <<= 1) {
        int u = 0;
        if (t >= off) u = tsum[t - off];
        __syncthreads();
        tsum[t] += u;
        __syncthreads();
    }
    int rbase = beg + tsum[t] - mysum;
    float di0 = rsqrtf(fmaxf((float)c0, 1.0f));
    float di1 = rsqrtf(fmaxf((float)c1, 1.0f));
    int d = d0 + 2 * t;
    if (d < N) {
        row_ptr[d] = rbase;
        dinv[d] = di0;
    }
    if (d + 1 < N) {
        row_ptr[d + 1] = rbase + c0;
        dinv[d + 1] = di1;
    }
    cnt[2 * t] = rbase;
    cnt[2 * t + 1] = rbase + c0;
    __syncthreads();
    for (int i = beg + t; i < end; i += 256) {
        int2 e = eb[i];
        int p = atomicAdd(&cnt[e.y - d0], 1);
        col[p] = e.x;
    }
    if (b == NB - 1 && t == 0) row_ptr[N] = E;
    // fused: scaled bf16 feature rows for this bucket
    __syncthreads();
    ((float*)cnt)[2 * t] = di0;
    ((float*)cnt)[2 * t + 1] = di1;
    __syncthreads();
    int nmax = N - d0;
    if (nmax > BSZ) nmax = BSZ;
    for (int i = t; i < nmax * 16; i += 256) {
        int nl = i >> 4, f4 = (i & 15) * 4;
        float s = ((float*)cnt)[nl];
        float4 v = *(const float4*)&features[(size_t)(d0 + nl) * 64 + f4];
        ushort4 o;
        o.x = f2bf(v.x * s); o.y = f2bf(v.y * s); o.z = f2bf(v.z * s); o.w = f2bf(v.w * s);
        *(ushort4*)&Fb[(size_t)(d0 + nl) * 64 + f4] = o;
    }
}

// ---------- weight prep: fp32 -> bf16 transposed ----------
__global__ void k_wprep(const float* __restrict__ W1, const float* __restrict__ W2,
                        const float* __restrict__ Wm1, const float* __restrict__ Wm2,
                        ushort_t* __restrict__ W1t, ushort_t* __restrict__ W2t,
                        ushort_t* __restrict__ Wm1t, ushort_t* __restrict__ Wm2t) {
    int i = blockIdx.x * 256 + threadIdx.x;
    if (i < 12288) { int k = i >> 6, n = i & 63; W1t[n * 192 + k] = f2bf(W1[i]); return; }
    i -= 12288;
    if (i < 12288) { int k = i >> 6, n = i & 63; W2t[n * 192 + k] = f2bf(W2[i]); return; }
    i -= 12288;
    if (i < 4096) { int k = i >> 6, n = i & 63; Wm1t[n * 64 + k] = f2bf(Wm1[i]); return; }
    i -= 4096;
    if (i < 2048) { int k = i >> 5, n = i & 31; Wm2t[n * 64 + k] = f2bf(Wm2[i]); }
}

// ---------- propagation (R10 4-group) ----------
// MODE 1: OUTB = bf16(-di^2 * S) (scaled); MODE 2: OUTB = bf16(-2*di*S - X0/di)
template <int MODE>
__global__ __launch_bounds__(256) void k_prop(
    const ushort_t* __restrict__ Xb, const int* __restrict__ rp,
    const int* __restrict__ col, const float* __restrict__ dinv,
    const ushort_t* __restrict__ X0b, ushort_t* __restrict__ OUTB, int N) {
    int wid = (blockIdx.x * blockDim.x + threadIdx.x) >> 6;
    int lane = threadIdx.x & 63;
    if (wid >= N) return;
    int g = lane >> 4;
    int fl = (lane & 15) * 4;
    int beg = rp[wid], end = rp[wid + 1];
    float4 a0 = make_float4(0.f, 0.f, 0.f, 0.f);
    float4 a1 = make_float4(0.f, 0.f, 0.f, 0.f);
    int e = beg + g;
    for (; e + 4 < end; e += 8) {
        int s0 = col[e], s1 = col[e + 4];
        ushort4 u0 = *(const ushort4*)&Xb[(size_t)s0 * 64 + fl];
        ushort4 u1 = *(const ushort4*)&Xb[(size_t)s1 * 64 + fl];
        a0.x += bf2f(u0.x); a0.y += bf2f(u0.y); a0.z += bf2f(u0.z); a0.w += bf2f(u0.w);
        a1.x += bf2f(u1.x); a1.y += bf2f(u1.y); a1.z += bf2f(u1.z); a1.w += bf2f(u1.w);
    }
    if (e < end) {
        int s0 = col[e];
        ushort4 u0 = *(const ushort4*)&Xb[(size_t)s0 * 64 + fl];
        a0.x += bf2f(u0.x); a0.y += bf2f(u0.y); a0.z += bf2f(u0.z); a0.w += bf2f(u0.w);
    }
    float4 acc;
    acc.x = a0.x + a1.x;
    acc.y = a0.y + a1.y;
    acc.z = a0.z + a1.z;
    acc.w = a0.w + a1.w;
    acc.x += __shfl_xor(acc.x, 16);
    acc.y += __shfl_xor(acc.y, 16);
    acc.z += __shfl_xor(acc.z, 16);
    acc.w += __shfl_xor(acc.w, 16);
    acc.x += __shfl_xor(acc.x, 32);
    acc.y += __shfl_xor(acc.y, 32);
    acc.z += __shfl_xor(acc.z, 32);
    acc.w += __shfl_xor(acc.w, 32);
    if (g == 0) {
        float di = dinv[wid];
        ushort4 ob;
        if (MODE == 1) {
            float m = -di * di;
            ob.x = f2bf(m * acc.x);
            ob.y = f2bf(m * acc.y);
            ob.z = f2bf(m * acc.z);
            ob.w = f2bf(m * acc.w);
        } else {
            ushort4 x0u = *(const ushort4*)&X0b[(size_t)wid * 64 + fl];
            float m = -2.0f * di;
            float rd = 1.0f / di;
            ob.x = f2bf(fmaf(m, acc.x, -rd * bf2f(x0u.x)));
            ob.y = f2bf(fmaf(m, acc.y, -rd * bf2f(x0u.y)));
            ob.z = f2bf(fmaf(m, acc.z, -rd * bf2f(x0u.z)));
            ob.w = f2bf(fmaf(m, acc.w, -rd * bf2f(x0u.w)));
        }
        *(ushort4*)&OUTB[(size_t)wid * 64 + fl] = ob;
    }
}

// ---------- cheb linear via MFMA (R10) ----------
template <bool SCALE_OUT>
__global__ __launch_bounds__(256) void k_cheb_mfma(
    const ushort_t* __restrict__ X0, const ushort_t* __restrict__ X1,
    const ushort_t* __restrict__ X2, const float* __restrict__ dinv,
    const ushort_t* __restrict__ Wt, const float* __restrict__ b,
    ushort_t* __restrict__ Yb, int N) {
    int wave = threadIdx.x >> 6, lane = threadIdx.x & 63;
    int n16 = lane & 15, q = lane >> 4;
    int node0 = blockIdx.x * 64;
    int arow = node0 + wave * 16 + n16;
    const ushort_t* Xc[3] = {X0, X1, X2};

    v4f acc_s[4], acc_u[4];
#pragma unroll
    for (int t = 0; t < 4; t++) {
        acc_s[t] = (v4f){0.f, 0.f, 0.f, 0.f};
        acc_u[t] = (v4f){0.f, 0.f, 0.f, 0.f};
    }
#pragma unroll
    for (int ks = 0; ks < 6; ks++) {
        int c = ks >> 1;
        int kk = (ks & 1) * 32 + q * 8;
        v8s av = {0, 0, 0, 0, 0, 0, 0, 0};
        if (arow < N) av = *(const v8s*)&Xc[c][(size_t)arow * 64 + kk];
#pragma unroll
        for (int t = 0; t < 4; t++) {
            v8s bv = *(const v8s*)&Wt[(size_t)(t * 16 + n16) * 192 + ks * 32 + q * 8];
            if (c < 2)
                acc_s[t] = __builtin_amdgcn_mfma_f32_16x16x32_bf16(av, bv, acc_s[t], 0, 0, 0);
            else
                acc_u[t] = __builtin_amdgcn_mfma_f32_16x16x32_bf16(av, bv, acc_u[t], 0, 0, 0);
        }
    }
    int rbase = node0 + wave * 16 + q * 4;
#pragma unroll
    for (int r = 0; r < 4; r++) {
        int row = rbase + r;
        if (row < N) {
            float dv = dinv[row];
            float rd = 1.0f / dv;
            float s = SCALE_OUT ? dv : 1.0f;
#pragma unroll
            for (int t = 0; t < 4; t++) {
                float y = fmaf(rd, acc_s[t][r], acc_u[t][r]) + b[t * 16 + n16];
                y = fmaxf(y, 0.0f);
                Yb[(size_t)row * 64 + t * 16 + n16] = f2bf(s * y);
            }
        }
    }
}

// ---------- MLP head via MFMA (R10) ----------
__global__ __launch_bounds__(256) void k_mlp_mfma(
    const ushort_t* __restrict__ Hb, const ushort_t* __restrict__ W1t,
    const float* __restrict__ b1, const ushort_t* __restrict__ W2t,
    const float* __restrict__ b2, float* __restrict__ out, int N) {
    __shared__ ushort_t Hs[64][76];
    int wave = threadIdx.x >> 6, lane = threadIdx.x & 63;
    int n16 = lane & 15, q = lane >> 4;
    int node0 = blockIdx.x * 64;
    int arow = node0 + wave * 16 + n16;

    v4f acc[4];
#pragma unroll
    for (int t = 0; t < 4; t++) acc[t] = (v4f){0.f, 0.f, 0.f, 0.f};
#pragma unroll
    for (int ks = 0; ks < 2; ks++) {
        v8s av = {0, 0, 0, 0, 0, 0, 0, 0};
        if (arow < N) av = *(const v8s*)&Hb[(size_t)arow * 64 + ks * 32 + q * 8];
#pragma unroll
        for (int t = 0; t < 4; t++) {
            v8s bv = *(const v8s*)&W1t[(size_t)(t * 16 + n16) * 64 + ks * 32 + q * 8];
            acc[t] = __builtin_amdgcn_mfma_f32_16x16x32_bf16(av, bv, acc[t], 0, 0, 0);
        }
    }
    int lr = wave * 16 + q * 4;
#pragma unroll
    for (int r = 0; r < 4; r++)
#pragma unroll
        for (int t = 0; t < 4; t++) {
            float y = acc[t][r] + b1[t * 16 + n16];
            Hs[lr + r][t * 16 + n16] = f2bf(fmaxf(y, 0.0f));
        }
    __syncthreads();

    v4f a2[2];
    a2[0] = (v4f){0.f, 0.f, 0.f, 0.f};
    a2[1] = (v4f){0.f, 0.f, 0.f, 0.f};
#pragma unroll
    for (int ks = 0; ks < 2; ks++) {
        v8s av = *(const v8s*)&Hs[wave * 16 + n16][ks * 32 + q * 8];
#pragma unroll
        for (int t = 0; t < 2; t++) {
            v8s bv = *(const v8s*)&W2t[(size_t)(t * 16 + n16) * 64 + ks * 32 + q * 8];
            a2[t] = __builtin_amdgcn_mfma_f32_16x16x32_bf16(av, bv, a2[t], 0, 0, 0);
        }
    }
    int rbase = node0 + wave * 16 + q * 4;
#pragma unroll
    for (int r = 0; r < 4; r++) {
        int row = rbase + r;
        if (row < N) {
#pragma unroll
            for (int t = 0; t < 2; t++)
                out[(size_t)row * 32 + t * 16 + n16] = a2[t][r] + b2[t * 16 + n16];
        }
    }
}

extern "C" void kernel_launch(void* const* d_in, const int* in_sizes, int n_in,
                              void* d_out, int out_size, void* d_ws, size_t ws_size,
                              hipStream_t stream) {
    const float* features = (const float*)d_in[0];
    const int* src = (const int*)d_in[1];
    const int* dst = (const int*)d_in[2];
    const float* W1 = (const float*)d_in[4];
    const float* b1 = (const float*)d_in[5];
    const float* W2 = (const float*)d_in[6];
    const float* b2 = (const float*)d_in[7];
    const float* Wm1 = (const float*)d_in[8];
    const float* bm1 = (const float*)d_in[9];
    const float* Wm2 = (const float*)d_in[10];
    const float* bm2 = (const float*)d_in[11];
    float* out = (float*)d_out;

    int N = in_sizes[0] / 64;
    int E = in_sizes[1];
    int NB = (N + BSZ - 1) >> BSH;

    float* ws = (float*)d_ws;
    float* dinv = ws;                           // [N]
    int* row_ptr = (int*)(dinv + N);            // [N+1]
    int* gbase = row_ptr + (N + 1);             // [1024]
    int* gcur = gbase + 1024;                   // [1024]
    int* col = gcur + 1024;                     // [E]
    int2* eb = (int2*)(((uintptr_t)(col + E) + 7) & ~(uintptr_t)7);  // [E]
    ushort_t* Fb  = (ushort_t*)(eb + E);        // [N*64] scaled
    ushort_t* X1b = Fb  + (size_t)N * 64;       // scaled
    ushort_t* X2b = X1b + (size_t)N * 64;       // unscaled
    ushort_t* H1b = X2b + (size_t)N * 64;       // scaled
    ushort_t* H2b = H1b + (size_t)N * 64;       // unscaled
    ushort_t* W1t = H2b + (size_t)N * 64;       // [64*192]
    ushort_t* W2t = W1t + 64 * 192;
    ushort_t* Wm1t = W2t + 64 * 192;            // [64*64]
    ushort_t* Wm2t = Wm1t + 64 * 64;            // [32*64]

    int pblk = (N * 64 + 255) / 256;
    int gblk = (N + 63) / 64;
    int bblk = (E + CHUNK - 1) / CHUNK;

    // weight prep
    k_wprep<<<(30720 + 255) / 256, 256, 0, stream>>>(W1, W2, Wm1, Wm2, W1t, W2t, Wm1t, Wm2t);

    // CSR build (R10) + fused feature shadow
    hipMemsetAsync(gbase, 0, NB * sizeof(int), stream);
    k_bhist<<<512, 256, 0, stream>>>(dst, gbase, E, NB);
    k_bscan<<<1, 1024, 0, stream>>>(gbase, gcur, NB);
    k_bucket2<<<bblk, 256, 0, stream>>>(src, dst, gcur, eb, E, NB);
    k_local<<<NB, 256, 0, stream>>>(eb, gbase, col, row_ptr, dinv, features, Fb, N, E, NB);

    // layer 1
    k_prop<1><<<pblk, 256, 0, stream>>>(Fb, row_ptr, col, dinv, nullptr, X1b, N);
    k_prop<2><<<pblk, 256, 0, stream>>>(X1b, row_ptr, col, dinv, Fb, X2b, N);
    k_cheb_mfma<true><<<gblk, 256, 0, stream>>>(Fb, X1b, X2b, dinv, W1t, b1, H1b, N);

    // layer 2
    k_prop<1><<<pblk, 256, 0, stream>>>(H1b, row_ptr, col, dinv, nullptr, X1b, N);
    k_prop<2><<<pblk, 256, 0, stream>>>(X1b, row_ptr, col, dinv, H1b, X2b, N);
    k_cheb_mfma<false><<<gblk, 256, 0, stream>>>(H1b, X1b, X2b, dinv, W2t, b2, H2b, N);

    // MLP head
    k_mlp_mfma<<<gblk, 256, 0, stream>>>(H2b, Wm1t, bm1, Wm2t, bm2, out, N);
}

// Round 15
// 391.258 us; speedup vs baseline: 1.1724x; 1.0403x over previous
//
#include <hip/hip_runtime.h>

// ChebNet round 15: exact R10 (measured best, 396us) with the gbase memset
// folded into k_wprep (one fewer dispatch). R14 lesson: do NOT fuse the
// feature->bf16 streaming into narrow-grid k_local (tail-heavy, -11us).
// Props pinned at 2.8 TB/s random-gather fabric ceiling (44us x4, stable
// across R10/R11/R14). GEMMs = MFMA. CSR = line-local two-pass sort.

typedef unsigned short ushort_t;
typedef __attribute__((ext_vector_type(8))) short v8s;
typedef __attribute__((ext_vector_type(4))) float v4f;

__device__ inline ushort_t f2bf(float f) {  // RNE float->bf16
    unsigned u = __float_as_uint(f);
    return (ushort_t)((u + 0x7FFFu + ((u >> 16) & 1u)) >> 16);
}
__device__ inline float bf2f(ushort_t h) {
    return __uint_as_float(((unsigned)h) << 16);
}

#define BSH 9
#define BSZ (1 << BSH)
#define CHUNK 4096

// ---------- weight prep + gbase zeroing (replaces memset dispatch) ----------
__global__ void k_wprep(const float* __restrict__ W1, const float* __restrict__ W2,
                        const float* __restrict__ Wm1, const float* __restrict__ Wm2,
                        ushort_t* __restrict__ W1t, ushort_t* __restrict__ W2t,
                        ushort_t* __restrict__ Wm1t, ushort_t* __restrict__ Wm2t,
                        int* __restrict__ gbase, int NB) {
    int i = blockIdx.x * 256 + threadIdx.x;
    if (i < 12288) { int k = i >> 6, n = i & 63; W1t[n * 192 + k] = f2bf(W1[i]); return; }
    i -= 12288;
    if (i < 12288) { int k = i >> 6, n = i & 63; W2t[n * 192 + k] = f2bf(W2[i]); return; }
    i -= 12288;
    if (i < 4096) { int k = i >> 6, n = i & 63; Wm1t[n * 64 + k] = f2bf(Wm1[i]); return; }
    i -= 4096;
    if (i < 2048) { int k = i >> 5, n = i & 31; Wm2t[n * 64 + k] = f2bf(Wm2[i]); return; }
    i -= 2048;
    if (i < NB) gbase[i] = 0;
}

// ---------- CSR build (R10, measured-good) ----------

__global__ __launch_bounds__(256) void k_bhist(const int* __restrict__ dst,
                                               int* __restrict__ gbase, int E, int NB) {
    __shared__ int h[1024];
    for (int i = threadIdx.x; i < NB; i += 256) h[i] = 0;
    __syncthreads();
    for (int i = blockIdx.x * blockDim.x + threadIdx.x; i < E; i += gridDim.x * blockDim.x)
        atomicAdd(&h[dst[i] >> BSH], 1);
    __syncthreads();
    for (int i = threadIdx.x; i < NB; i += 256)
        if (h[i]) atomicAdd(&gbase[i], h[i]);
}

__global__ void k_bscan(int* __restrict__ gbase, int* __restrict__ gcur, int NB) {
    __shared__ int sh[1024];
    int t = threadIdx.x;
    int v = (t < NB) ? gbase[t] : 0;
    sh[t] = v;
    __syncthreads();
    for (int off = 1; off < 1024; off <<= 1) {
        int u = 0;
        if (t >= off) u = sh[t - off];
        __syncthreads();
        sh[t] += u;
        __syncthreads();
    }
    if (t < NB) {
        int excl = sh[t] - v;
        gbase[t] = excl;
        gcur[t] = excl;
    }
}

__global__ __launch_bounds__(256) void k_bucket2(
    const int* __restrict__ src, const int* __restrict__ dst,
    int* __restrict__ gcur, int2* __restrict__ eb, int E, int NB) {
    __shared__ int ls[CHUNK];
    __shared__ int ld[CHUNK];
    __shared__ int hist[1024];
    __shared__ int bbase[1024];
    int t = threadIdx.x;
    int base = blockIdx.x * CHUNK;
    int count = E - base;
    if (count > CHUNK) count = CHUNK;
    for (int i = t; i < NB; i += 256) hist[i] = 0;
    __syncthreads();
    for (int i = t; i < count; i += 256) {
        int s = src[base + i];
        int d = dst[base + i];
        ls[i] = s;
        ld[i] = d;
        atomicAdd(&hist[d >> BSH], 1);
    }
    __syncthreads();
    for (int b = t; b < NB; b += 256) {
        int c = hist[b];
        bbase[b] = c ? atomicAdd(&gcur[b], c) : 0;
        hist[b] = 0;
    }
    __syncthreads();
    for (int i = t; i < count; i += 256) {
        int d = ld[i];
        int b = d >> BSH;
        int off = atomicAdd(&hist[b], 1);
        eb[bbase[b] + off] = make_int2(ls[i], d);
    }
}

__global__ __launch_bounds__(256) void k_local(
    const int2* __restrict__ eb, const int* __restrict__ gbase,
    int* __restrict__ col, int* __restrict__ row_ptr,
    float* __restrict__ dinv, int N, int E, int NB) {
    __shared__ int cnt[BSZ];
    __shared__ int tsum[256];
    int t = threadIdx.x;
    int b = blockIdx.x;
    int d0 = b << BSH;
    cnt[2 * t] = 0;
    cnt[2 * t + 1] = 0;
    __syncthreads();
    int beg = gbase[b];
    int end = (b + 1 < NB) ? gbase[b + 1] : E;
    for (int i = beg + t; i < end; i += 256)
        atomicAdd(&cnt[eb[i].y - d0], 1);
    __syncthreads();
    int c0 = cnt[2 * t], c1 = cnt[2 * t + 1];
    int mysum = c0 + c1;
    tsum[t] = mysum;
    __syncthreads();
    for (int off = 1; off < 256; off <<= 1) {
        int u = 0;
        if (t >= off) u = tsum[t - off];
        __syncthreads();
        tsum[t] += u;
        __syncthreads();
    }
    int rbase = beg + tsum[t] - mysum;
    int d = d0 + 2 * t;
    if (d < N) {
        row_ptr[d] = rbase;
        dinv[d] = rsqrtf(fmaxf((float)c0, 1.0f));
    }
    if (d + 1 < N) {
        row_ptr[d + 1] = rbase + c0;
        dinv[d + 1] = rsqrtf(fmaxf((float)c1, 1.0f));
    }
    cnt[2 * t] = rbase;
    cnt[2 * t + 1] = rbase + c0;
    __syncthreads();
    for (int i = beg + t; i < end; i += 256) {
        int2 e = eb[i];
        int p = atomicAdd(&cnt[e.y - d0], 1);
        col[p] = e.x;
    }
    if (b == NB - 1 && t == 0) row_ptr[N] = E;
}

// ---------- fp32 -> scaled bf16 shadow (standalone, wide grid) ----------
__global__ void k_tobf16(const float4* __restrict__ X, const float* __restrict__ dinv,
                         ushort4* __restrict__ Y, int n4) {
    int i = blockIdx.x * blockDim.x + threadIdx.x;
    if (i < n4) {
        float s = dinv[i >> 4];
        float4 v = X[i];
        ushort4 o;
        o.x = f2bf(v.x * s); o.y = f2bf(v.y * s); o.z = f2bf(v.z * s); o.w = f2bf(v.w * s);
        Y[i] = o;
    }
}

// ---------- propagation (R10 4-group) ----------
// MODE 1: OUTB = bf16(-di^2 * S) (scaled); MODE 2: OUTB = bf16(-2*di*S - X0/di)
template <int MODE>
__global__ __launch_bounds__(256) void k_prop(
    const ushort_t* __restrict__ Xb, const int* __restrict__ rp,
    const int* __restrict__ col, const float* __restrict__ dinv,
    const ushort_t* __restrict__ X0b, ushort_t* __restrict__ OUTB, int N) {
    int wid = (blockIdx.x * blockDim.x + threadIdx.x) >> 6;
    int lane = threadIdx.x & 63;
    if (wid >= N) return;
    int g = lane >> 4;
    int fl = (lane & 15) * 4;
    int beg = rp[wid], end = rp[wid + 1];
    float4 a0 = make_float4(0.f, 0.f, 0.f, 0.f);
    float4 a1 = make_float4(0.f, 0.f, 0.f, 0.f);
    int e = beg + g;
    for (; e + 4 < end; e += 8) {
        int s0 = col[e], s1 = col[e + 4];
        ushort4 u0 = *(const ushort4*)&Xb[(size_t)s0 * 64 + fl];
        ushort4 u1 = *(const ushort4*)&Xb[(size_t)s1 * 64 + fl];
        a0.x += bf2f(u0.x); a0.y += bf2f(u0.y); a0.z += bf2f(u0.z); a0.w += bf2f(u0.w);
        a1.x += bf2f(u1.x); a1.y += bf2f(u1.y); a1.z += bf2f(u1.z); a1.w += bf2f(u1.w);
    }
    if (e < end) {
        int s0 = col[e];
        ushort4 u0 = *(const ushort4*)&Xb[(size_t)s0 * 64 + fl];
        a0.x += bf2f(u0.x); a0.y += bf2f(u0.y); a0.z += bf2f(u0.z); a0.w += bf2f(u0.w);
    }
    float4 acc;
    acc.x = a0.x + a1.x;
    acc.y = a0.y + a1.y;
    acc.z = a0.z + a1.z;
    acc.w = a0.w + a1.w;
    acc.x += __shfl_xor(acc.x, 16);
    acc.y += __shfl_xor(acc.y, 16);
    acc.z += __shfl_xor(acc.z, 16);
    acc.w += __shfl_xor(acc.w, 16);
    acc.x += __shfl_xor(acc.x, 32);
    acc.y += __shfl_xor(acc.y, 32);
    acc.z += __shfl_xor(acc.z, 32);
    acc.w += __shfl_xor(acc.w, 32);
    if (g == 0) {
        float di = dinv[wid];
        ushort4 ob;
        if (MODE == 1) {
            float m = -di * di;
            ob.x = f2bf(m * acc.x);
            ob.y = f2bf(m * acc.y);
            ob.z = f2bf(m * acc.z);
            ob.w = f2bf(m * acc.w);
        } else {
            ushort4 x0u = *(const ushort4*)&X0b[(size_t)wid * 64 + fl];
            float m = -2.0f * di;
            float rd = 1.0f / di;
            ob.x = f2bf(fmaf(m, acc.x, -rd * bf2f(x0u.x)));
            ob.y = f2bf(fmaf(m, acc.y, -rd * bf2f(x0u.y)));
            ob.z = f2bf(fmaf(m, acc.z, -rd * bf2f(x0u.z)));
            ob.w = f2bf(fmaf(m, acc.w, -rd * bf2f(x0u.w)));
        }
        *(ushort4*)&OUTB[(size_t)wid * 64 + fl] = ob;
    }
}

// ---------- cheb linear via MFMA (R10) ----------
template <bool SCALE_OUT>
__global__ __launch_bounds__(256) void k_cheb_mfma(
    const ushort_t* __restrict__ X0, const ushort_t* __restrict__ X1,
    const ushort_t* __restrict__ X2, const float* __restrict__ dinv,
    const ushort_t* __restrict__ Wt, const float* __restrict__ b,
    ushort_t* __restrict__ Yb, int N) {
    int wave = threadIdx.x >> 6, lane = threadIdx.x & 63;
    int n16 = lane & 15, q = lane >> 4;
    int node0 = blockIdx.x * 64;
    int arow = node0 + wave * 16 + n16;
    const ushort_t* Xc[3] = {X0, X1, X2};

    v4f acc_s[4], acc_u[4];
#pragma unroll
    for (int t = 0; t < 4; t++) {
        acc_s[t] = (v4f){0.f, 0.f, 0.f, 0.f};
        acc_u[t] = (v4f){0.f, 0.f, 0.f, 0.f};
    }
#pragma unroll
    for (int ks = 0; ks < 6; ks++) {
        int c = ks >> 1;
        int kk = (ks & 1) * 32 + q * 8;
        v8s av = {0, 0, 0, 0, 0, 0, 0, 0};
        if (arow < N) av = *(const v8s*)&Xc[c][(size_t)arow * 64 + kk];
#pragma unroll
        for (int t = 0; t < 4; t++) {
            v8s bv = *(const v8s*)&Wt[(size_t)(t * 16 + n16) * 192 + ks * 32 + q * 8];
            if (c < 2)
                acc_s[t] = __builtin_amdgcn_mfma_f32_16x16x32_bf16(av, bv, acc_s[t], 0, 0, 0);
            else
                acc_u[t] = __builtin_amdgcn_mfma_f32_16x16x32_bf16(av, bv, acc_u[t], 0, 0, 0);
        }
    }
    int rbase = node0 + wave * 16 + q * 4;
#pragma unroll
    for (int r = 0; r < 4; r++) {
        int row = rbase + r;
        if (row < N) {
            float dv = dinv[row];
            float rd = 1.0f / dv;
            float s = SCALE_OUT ? dv : 1.0f;
#pragma unroll
            for (int t = 0; t < 4; t++) {
                float y = fmaf(rd, acc_s[t][r], acc_u[t][r]) + b[t * 16 + n16];
                y = fmaxf(y, 0.0f);
                Yb[(size_t)row * 64 + t * 16 + n16] = f2bf(s * y);
            }
        }
    }
}

// ---------- MLP head via MFMA (R10) ----------
__global__ __launch_bounds__(256) void k_mlp_mfma(
    const ushort_t* __restrict__ Hb, const ushort_t* __restrict__ W1t,
    const float* __restrict__ b1, const ushort_t* __restrict__ W2t,
    const float* __restrict__ b2, float* __restrict__ out, int N) {
    __shared__ ushort_t Hs[64][76];
    int wave = threadIdx.x >> 6, lane = threadIdx.x & 63;
    int n16 = lane & 15, q = lane >> 4;
    int node0 = blockIdx.x * 64;
    int arow = node0 + wave * 16 + n16;

    v4f acc[4];
#pragma unroll
    for (int t = 0; t < 4; t++) acc[t] = (v4f){0.f, 0.f, 0.f, 0.f};
#pragma unroll
    for (int ks = 0; ks < 2; ks++) {
        v8s av = {0, 0, 0, 0, 0, 0, 0, 0};
        if (arow < N) av = *(const v8s*)&Hb[(size_t)arow * 64 + ks * 32 + q * 8];
#pragma unroll
        for (int t = 0; t < 4; t++) {
            v8s bv = *(const v8s*)&W1t[(size_t)(t * 16 + n16) * 64 + ks * 32 + q * 8];
            acc[t] = __builtin_amdgcn_mfma_f32_16x16x32_bf16(av, bv, acc[t], 0, 0, 0);
        }
    }
    int lr = wave * 16 + q * 4;
#pragma unroll
    for (int r = 0; r < 4; r++)
#pragma unroll
        for (int t = 0; t < 4; t++) {
            float y = acc[t][r] + b1[t * 16 + n16];
            Hs[lr + r][t * 16 + n16] = f2bf(fmaxf(y, 0.0f));
        }
    __syncthreads();

    v4f a2[2];
    a2[0] = (v4f){0.f, 0.f, 0.f, 0.f};
    a2[1] = (v4f){0.f, 0.f, 0.f, 0.f};
#pragma unroll
    for (int ks = 0; ks < 2; ks++) {
        v8s av = *(const v8s*)&Hs[wave * 16 + n16][ks * 32 + q * 8];
#pragma unroll
        for (int t = 0; t < 2; t++) {
            v8s bv = *(const v8s*)&W2t[(size_t)(t * 16 + n16) * 64 + ks * 32 + q * 8];
            a2[t] = __builtin_amdgcn_mfma_f32_16x16x32_bf16(av, bv, a2[t], 0, 0, 0);
        }
    }
    int rbase = node0 + wave * 16 + q * 4;
#pragma unroll
    for (int r = 0; r < 4; r++) {
        int row = rbase + r;
        if (row < N) {
#pragma unroll
            for (int t = 0; t < 2; t++)
                out[(size_t)row * 32 + t * 16 + n16] = a2[t][r] + b2[t * 16 + n16];
        }
    }
}

extern "C" void kernel_launch(void* const* d_in, const int* in_sizes, int n_in,
                              void* d_out, int out_size, void* d_ws, size_t ws_size,
                              hipStream_t stream) {
    const float* features = (const float*)d_in[0];
    const int* src = (const int*)d_in[1];
    const int* dst = (const int*)d_in[2];
    const float* W1 = (const float*)d_in[4];
    const float* b1 = (const float*)d_in[5];
    const float* W2 = (const float*)d_in[6];
    const float* b2 = (const float*)d_in[7];
    const float* Wm1 = (const float*)d_in[8];
    const float* bm1 = (const float*)d_in[9];
    const float* Wm2 = (const float*)d_in[10];
    const float* bm2 = (const float*)d_in[11];
    float* out = (float*)d_out;

    int N = in_sizes[0] / 64;
    int E = in_sizes[1];
    int NB = (N + BSZ - 1) >> BSH;

    float* ws = (float*)d_ws;
    float* dinv = ws;                           // [N]
    int* row_ptr = (int*)(dinv + N);            // [N+1]
    int* gbase = row_ptr + (N + 1);             // [1024]
    int* gcur = gbase + 1024;                   // [1024]
    int* col = gcur + 1024;                     // [E]
    int2* eb = (int2*)(((uintptr_t)(col + E) + 7) & ~(uintptr_t)7);  // [E]
    ushort_t* Fb  = (ushort_t*)(eb + E);        // [N*64] scaled
    ushort_t* X1b = Fb  + (size_t)N * 64;       // scaled
    ushort_t* X2b = X1b + (size_t)N * 64;       // unscaled
    ushort_t* H1b = X2b + (size_t)N * 64;       // scaled
    ushort_t* H2b = H1b + (size_t)N * 64;       // unscaled
    ushort_t* W1t = H2b + (size_t)N * 64;       // [64*192]
    ushort_t* W2t = W1t + 64 * 192;
    ushort_t* Wm1t = W2t + 64 * 192;            // [64*64]
    ushort_t* Wm2t = Wm1t + 64 * 64;            // [32*64]

    int pblk = (N * 64 + 255) / 256;
    int gblk = (N + 63) / 64;
    int n4 = N * 16;
    int cblk = (n4 + 255) / 256;
    int bblk = (E + CHUNK - 1) / CHUNK;

    // weight prep + gbase zeroing (one dispatch)
    k_wprep<<<(30720 + 1024 + 255) / 256, 256, 0, stream>>>(
        W1, W2, Wm1, Wm2, W1t, W2t, Wm1t, Wm2t, gbase, NB);

    // CSR build (R10)
    k_bhist<<<512, 256, 0, stream>>>(dst, gbase, E, NB);
    k_bscan<<<1, 1024, 0, stream>>>(gbase, gcur, NB);
    k_bucket2<<<bblk, 256, 0, stream>>>(src, dst, gcur, eb, E, NB);
    k_local<<<NB, 256, 0, stream>>>(eb, gbase, col, row_ptr, dinv, N, E, NB);

    // scaled bf16 shadow of features (wide grid)
    k_tobf16<<<cblk, 256, 0, stream>>>((const float4*)features, dinv, (ushort4*)Fb, n4);

    // layer 1
    k_prop<1><<<pblk, 256, 0, stream>>>(Fb, row_ptr, col, dinv, nullptr, X1b, N);
    k_prop<2><<<pblk, 256, 0, stream>>>(X1b, row_ptr, col, dinv, Fb, X2b, N);
    k_cheb_mfma<true><<<gblk, 256, 0, stream>>>(Fb, X1b, X2b, dinv, W1t, b1, H1b, N);

    // layer 2
    k_prop<1><<<pblk, 256, 0, stream>>>(H1b, row_ptr, col, dinv, nullptr, X1b, N);
    k_prop<2><<<pblk, 256, 0, stream>>>(X1b, row_ptr, col, dinv, H1b, X2b, N);
    k_cheb_mfma<false><<<gblk, 256, 0, stream>>>(H1b, X1b, X2b, dinv, W2t, b2, H2b, N);

    // MLP head
    k_mlp_mfma<<<gblk, 256, 0, stream>>>(H2b, Wm1t, bm1, Wm2t, bm2, out, N);
}